// Round 1
// baseline (121.799 us; speedup 1.0000x reference)
//
#include <hip/hip_runtime.h>

#define MODEL_D 1024
#define RANK    128
#define BATCH   8
#define SEQ     512
#define M_TOTAL (BATCH*SEQ)   // 4096

// ---------------- Kernel A: T = batch @ proj ----------------
// M=4096, K=1024, N=128. Block: 16 rows x 128 cols. 256 blocks x 256 threads.
// Per thread: 2 rows x 4 cols. K staged in LDS, chunk = 32.
__global__ __launch_bounds__(256) void proj_kernel(
    const float* __restrict__ batch, const float* __restrict__ proj,
    float* __restrict__ T)
{
    __shared__ float As[16 * 32];     // 16 rows x 32 k
    __shared__ float Ps[32 * 128];    // 32 k x 128 cols

    const int t    = threadIdx.x;
    const int row0 = blockIdx.x * 16;
    const int c4   = t & 31;          // float4 column group: cols c4*4..c4*4+3
    const int rg   = t >> 5;          // 0..7 -> rows rg*2, rg*2+1

    float4 acc0 = {0.f, 0.f, 0.f, 0.f};
    float4 acc1 = {0.f, 0.f, 0.f, 0.f};

    for (int k0 = 0; k0 < MODEL_D; k0 += 32) {
        // Stage A-tile: 16x32 floats; threads 0..127 load one float4 each.
        if (t < 128) {
            int i   = t >> 3;   // 0..15
            int kk4 = t & 7;    // 0..7
            float4 v = *(const float4*)(batch + (size_t)(row0 + i) * MODEL_D + k0 + kk4 * 4);
            *(float4*)(As + i * 32 + kk4 * 4) = v;
        }
        // Stage P-tile: 32x128 floats; each thread 4 float4 (coalesced over cols).
        {
            int cc = t & 31;    // f4 col 0..31
            int kb = t >> 5;    // 0..7
            #pragma unroll
            for (int m = 0; m < 4; ++m) {
                int kk = kb + 8 * m;
                float4 v = *(const float4*)(proj + (size_t)(k0 + kk) * RANK + cc * 4);
                *(float4*)(Ps + kk * 128 + cc * 4) = v;
            }
        }
        __syncthreads();

        #pragma unroll
        for (int kk4 = 0; kk4 < 8; ++kk4) {
            float4 a0 = *(const float4*)(As + (rg * 2 + 0) * 32 + kk4 * 4);
            float4 a1 = *(const float4*)(As + (rg * 2 + 1) * 32 + kk4 * 4);
            const float* a0f = (const float*)&a0;
            const float* a1f = (const float*)&a1;
            #pragma unroll
            for (int q = 0; q < 4; ++q) {
                float4 b = *(const float4*)(Ps + (kk4 * 4 + q) * 128 + c4 * 4);
                float x0 = a0f[q], x1 = a1f[q];
                acc0.x += x0 * b.x; acc0.y += x0 * b.y; acc0.z += x0 * b.z; acc0.w += x0 * b.w;
                acc1.x += x1 * b.x; acc1.y += x1 * b.y; acc1.z += x1 * b.z; acc1.w += x1 * b.w;
            }
        }
        __syncthreads();
    }

    *(float4*)(T + (size_t)(row0 + rg * 2 + 0) * RANK + c4 * 4) = acc0;
    *(float4*)(T + (size_t)(row0 + rg * 2 + 1) * RANK + c4 * 4) = acc1;
}

// ---------------- Kernel B: D[b,i,j] = nI + nJ - 2 * T_i . T_j ----------------
// Grid: (8 j-tiles, 8 i-tiles, 8 batches). Block: 256 threads, 64x64 output tile,
// 4x4 acc per thread. K = 128 fully resident in LDS (padded ld = 132).
#define LDT 132

__global__ __launch_bounds__(256) void dist_kernel(
    const float* __restrict__ T, float* __restrict__ D)
{
    __shared__ float Ti[64 * LDT];
    __shared__ float Tj[64 * LDT];
    __shared__ float nI[64];
    __shared__ float nJ[64];

    const int t  = threadIdx.x;
    const int jt = blockIdx.x, it = blockIdx.y, b = blockIdx.z;
    const int i0 = it * 64, j0 = jt * 64;
    const float* Tb = T + (size_t)b * SEQ * RANK;

    // Load both 64x128 tiles (float4, coalesced; 8 f4 per thread per tile).
    {
        int il = t >> 5;    // 0..7
        int k4 = t & 31;    // 0..31
        #pragma unroll
        for (int m = 0; m < 8; ++m) {
            int i = il + m * 8;
            float4 vi = *(const float4*)(Tb + (size_t)(i0 + i) * RANK + k4 * 4);
            float4 vj = *(const float4*)(Tb + (size_t)(j0 + i) * RANK + k4 * 4);
            *(float4*)(Ti + i * LDT + k4 * 4) = vi;
            *(float4*)(Tj + i * LDT + k4 * 4) = vj;
        }
    }
    __syncthreads();

    // Row norms from LDS (threads 0..63 -> nI, 64..127 -> nJ).
    if (t < 64) {
        float s = 0.f;
        #pragma unroll
        for (int k4 = 0; k4 < 32; ++k4) {
            float4 v = *(const float4*)(Ti + t * LDT + k4 * 4);
            s += v.x * v.x + v.y * v.y + v.z * v.z + v.w * v.w;
        }
        nI[t] = s;
    } else if (t < 128) {
        int j = t - 64;
        float s = 0.f;
        #pragma unroll
        for (int k4 = 0; k4 < 32; ++k4) {
            float4 v = *(const float4*)(Tj + j * LDT + k4 * 4);
            s += v.x * v.x + v.y * v.y + v.z * v.z + v.w * v.w;
        }
        nJ[j] = s;
    }
    __syncthreads();

    const int tx = t & 15;   // j group
    const int ty = t >> 4;   // i group
    float acc[4][4] = {};

    for (int k4 = 0; k4 < 32; ++k4) {
        float4 a[4], c[4];
        #pragma unroll
        for (int ii = 0; ii < 4; ++ii)
            a[ii] = *(const float4*)(Ti + (ty * 4 + ii) * LDT + k4 * 4);
        #pragma unroll
        for (int jj = 0; jj < 4; ++jj)
            c[jj] = *(const float4*)(Tj + (tx * 4 + jj) * LDT + k4 * 4);
        #pragma unroll
        for (int ii = 0; ii < 4; ++ii) {
            #pragma unroll
            for (int jj = 0; jj < 4; ++jj) {
                acc[ii][jj] += a[ii].x * c[jj].x + a[ii].y * c[jj].y
                             + a[ii].z * c[jj].z + a[ii].w * c[jj].w;
            }
        }
    }

    float* Db = D + (size_t)b * SEQ * SEQ;
    #pragma unroll
    for (int ii = 0; ii < 4; ++ii) {
        int i = i0 + ty * 4 + ii;
        float ni = nI[ty * 4 + ii];
        float4 o;
        o.x = ni + nJ[tx * 4 + 0] - 2.f * acc[ii][0];
        o.y = ni + nJ[tx * 4 + 1] - 2.f * acc[ii][1];
        o.z = ni + nJ[tx * 4 + 2] - 2.f * acc[ii][2];
        o.w = ni + nJ[tx * 4 + 3] - 2.f * acc[ii][3];
        *(float4*)(Db + (size_t)i * SEQ + j0 + tx * 4) = o;
    }
}

extern "C" void kernel_launch(void* const* d_in, const int* in_sizes, int n_in,
                              void* d_out, int out_size, void* d_ws, size_t ws_size,
                              hipStream_t stream) {
    const float* batch = (const float*)d_in[0];   // (8, 512, 1024) fp32
    const float* proj  = (const float*)d_in[1];   // (1024, 128) fp32
    float* out = (float*)d_out;                   // (8, 512, 512) fp32
    float* T   = (float*)d_ws;                    // 4096 x 128 fp32 = 2 MB scratch

    proj_kernel<<<M_TOTAL / 16, 256, 0, stream>>>(batch, proj, T);
    dist_kernel<<<dim3(8, 8, 8), 256, 0, stream>>>(T, out);
}

// Round 2
// 80.789 us; speedup vs baseline: 1.5076x; 1.5076x over previous
//
#include <hip/hip_runtime.h>

#define SEQ 512
#define MD  1024
#define RK  128

typedef __attribute__((ext_vector_type(8))) short  bf16x8;
typedef __attribute__((ext_vector_type(4))) float  floatx4;
typedef __attribute__((ext_vector_type(4))) unsigned int uint4v;
typedef __attribute__((ext_vector_type(4))) unsigned short ushortx4;

__device__ inline unsigned short f2bf(float f) {
    union { float f; unsigned u; } v; v.f = f;
    unsigned r = v.u + 0x7fffu + ((v.u >> 16) & 1u);   // RNE, inputs are normal
    return (unsigned short)(r >> 16);
}
__device__ inline float bf2f(unsigned short s) {
    union { unsigned u; float f; } v; v.u = ((unsigned)s) << 16;
    return v.f;
}

// ---------- Kernel 0: Pt[n][k] = bf16(proj[k][n]), 128 x 1024 ----------
__global__ __launch_bounds__(256) void transpose_proj(
    const float* __restrict__ proj, unsigned short* __restrict__ Pt)
{
    __shared__ float Ls[64 * 132];   // 64 k x 128 n, pad 132
    const int t  = threadIdx.x;
    const int k0 = blockIdx.x * 64;

    {   // coalesced read of 64x128 fp32 tile
        int kr = t >> 2;
        int nb = (t & 3) * 32;
        #pragma unroll
        for (int cc = 0; cc < 8; ++cc) {
            float4 v = *(const float4*)(proj + (size_t)(k0 + kr) * RK + nb + cc * 4);
            *(float4*)(Ls + kr * 132 + nb + cc * 4) = v;
        }
    }
    __syncthreads();
    {   // transposed write: thread -> row n, 32 k's
        int n  = t >> 1;
        int kh = (t & 1) * 32;
        unsigned short tmp[32];
        #pragma unroll
        for (int kk = 0; kk < 32; ++kk)
            tmp[kk] = f2bf(Ls[(kh + kk) * 132 + n]);
        #pragma unroll
        for (int q = 0; q < 4; ++q)
            *(uint4v*)(Pt + (size_t)n * MD + k0 + kh + q * 8) = *(uint4v*)(tmp + q * 8);
    }
}

// ---------- Kernel 1: T = bf16( batch @ proj ), via MFMA ----------
// 256 blocks x 512 threads (8 waves). Block owns 16 rows; wave w owns K-eighth.
// A-frags from HBM (cvt in reg), B-frags from L2-resident Pt. LDS only for the
// cross-wave fp32 reduction. No K-loop barriers.
__global__ __launch_bounds__(512) void proj_mfma(
    const float* __restrict__ batch, const unsigned short* __restrict__ Pt,
    unsigned short* __restrict__ T)
{
    __shared__ float Red[8 * 2048];   // 8 waves x (16 rows x 128 cols) fp32

    const int t    = threadIdx.x;
    const int w    = t >> 6;
    const int l    = t & 63;
    const int lm   = l & 15;
    const int quad = l >> 4;
    const int r0   = blockIdx.x * 16;

    floatx4 acc[8];
    #pragma unroll
    for (int i = 0; i < 8; ++i) acc[i] = (floatx4){0.f, 0.f, 0.f, 0.f};

    const float* arow = batch + (size_t)(r0 + lm) * MD + w * 128 + quad * 8;

    #pragma unroll
    for (int s = 0; s < 4; ++s) {
        // A fragment: lane holds A[m=lm][k = w*128 + s*32 + quad*8 + j]
        float4 a0 = *(const float4*)(arow + s * 32);
        float4 a1 = *(const float4*)(arow + s * 32 + 4);
        bf16x8 av;
        av[0] = (short)f2bf(a0.x); av[1] = (short)f2bf(a0.y);
        av[2] = (short)f2bf(a0.z); av[3] = (short)f2bf(a0.w);
        av[4] = (short)f2bf(a1.x); av[5] = (short)f2bf(a1.y);
        av[6] = (short)f2bf(a1.z); av[7] = (short)f2bf(a1.w);
        #pragma unroll
        for (int nt = 0; nt < 8; ++nt) {
            // B fragment: lane holds B[n = nt*16+lm][k] = Pt row, contiguous k
            bf16x8 bv = *(const bf16x8*)(Pt + (size_t)(nt * 16 + lm) * MD
                                         + w * 128 + s * 32 + quad * 8);
            acc[nt] = __builtin_amdgcn_mfma_f32_16x16x32_bf16(av, bv, acc[nt], 0, 0, 0);
        }
    }

    // dump per-wave partials: C/D layout row = quad*4+r, col = nt*16+lm
    #pragma unroll
    for (int nt = 0; nt < 8; ++nt) {
        #pragma unroll
        for (int r = 0; r < 4; ++r) {
            int elem = (quad * 4 + r) * 128 + nt * 16 + lm;
            Red[w * 2048 + elem] = acc[nt][r];
        }
    }
    __syncthreads();

    // reduce 8 partials -> bf16 T; thread t handles 4 contiguous elems
    {
        unsigned short tmp[4];
        #pragma unroll
        for (int i = 0; i < 4; ++i) {
            int e = t * 4 + i;
            float s = 0.f;
            #pragma unroll
            for (int ww = 0; ww < 8; ++ww) s += Red[ww * 2048 + e];
            tmp[i] = f2bf(s);
        }
        *(ushortx4*)(T + (size_t)r0 * RK + t * 4) = *(ushortx4*)tmp;
    }
}

// ---------- Kernel 2: D[b,i,j] = nI + nJ - 2 * (T_i . T_j), via MFMA ----------
// Grid (8 jt, 8 it, 8 b), 256 threads = 4 waves; 64x64 tile; wave w -> 16 i-rows.
#define LDB 136   // 128 + 8 bf16 pad: 16B-aligned rows, stride/16B = 17 (odd) -> 2-way only

__global__ __launch_bounds__(256) void dist_mfma(
    const unsigned short* __restrict__ T, float* __restrict__ out)
{
    __shared__ unsigned short Ti[64 * LDB];
    __shared__ unsigned short Tj[64 * LDB];
    __shared__ float nI[64], nJ[64];

    const int t    = threadIdx.x;
    const int w    = t >> 6;
    const int l    = t & 63;
    const int lm   = l & 15;
    const int quad = l >> 4;
    const int jt = blockIdx.x, it = blockIdx.y, b = blockIdx.z;
    const int i0 = it * 64, j0 = jt * 64;
    const unsigned short* Tb = T + (size_t)b * SEQ * RK;

    {   // stage both 64x128 bf16 tiles
        int row = t >> 2, kq = (t & 3) * 32;
        const unsigned short* si = Tb + (size_t)(i0 + row) * RK + kq;
        const unsigned short* sj = Tb + (size_t)(j0 + row) * RK + kq;
        #pragma unroll
        for (int q = 0; q < 4; ++q) {
            *(uint4v*)(Ti + row * LDB + kq + q * 8) = *(const uint4v*)(si + q * 8);
            *(uint4v*)(Tj + row * LDB + kq + q * 8) = *(const uint4v*)(sj + q * 8);
        }
    }
    __syncthreads();

    // row norms from the (bf16) tiles -> consistent with Gram, D[i][i] ~ 0
    if (t < 64) {
        float s = 0.f;
        #pragma unroll
        for (int k8 = 0; k8 < 16; ++k8) {
            bf16x8 v = *(const bf16x8*)(Ti + t * LDB + k8 * 8);
            #pragma unroll
            for (int j = 0; j < 8; ++j) {
                float f = bf2f((unsigned short)v[j]); s += f * f;
            }
        }
        nI[t] = s;
    } else if (t < 128) {
        int r = t - 64;
        float s = 0.f;
        #pragma unroll
        for (int k8 = 0; k8 < 16; ++k8) {
            bf16x8 v = *(const bf16x8*)(Tj + r * LDB + k8 * 8);
            #pragma unroll
            for (int j = 0; j < 8; ++j) {
                float f = bf2f((unsigned short)v[j]); s += f * f;
            }
        }
        nJ[r] = s;
    }
    __syncthreads();

    floatx4 acc[4];
    #pragma unroll
    for (int i = 0; i < 4; ++i) acc[i] = (floatx4){0.f, 0.f, 0.f, 0.f};

    #pragma unroll
    for (int s = 0; s < 4; ++s) {
        bf16x8 av = *(const bf16x8*)(Ti + (w * 16 + lm) * LDB + s * 32 + quad * 8);
        #pragma unroll
        for (int nt = 0; nt < 4; ++nt) {
            bf16x8 bv = *(const bf16x8*)(Tj + (nt * 16 + lm) * LDB + s * 32 + quad * 8);
            acc[nt] = __builtin_amdgcn_mfma_f32_16x16x32_bf16(av, bv, acc[nt], 0, 0, 0);
        }
    }

    float niv[4];
    #pragma unroll
    for (int r = 0; r < 4; ++r) niv[r] = nI[w * 16 + quad * 4 + r];

    float* ob = out + ((size_t)b * SEQ + (i0 + w * 16)) * SEQ + j0;
    #pragma unroll
    for (int nt = 0; nt < 4; ++nt) {
        float njv = nJ[nt * 16 + lm];
        #pragma unroll
        for (int r = 0; r < 4; ++r) {
            ob[(size_t)(quad * 4 + r) * SEQ + nt * 16 + lm] =
                niv[r] + njv - 2.f * acc[nt][r];
        }
    }
}

extern "C" void kernel_launch(void* const* d_in, const int* in_sizes, int n_in,
                              void* d_out, int out_size, void* d_ws, size_t ws_size,
                              hipStream_t stream) {
    const float* batch = (const float*)d_in[0];   // (8, 512, 1024) fp32
    const float* proj  = (const float*)d_in[1];   // (1024, 128) fp32
    float* out = (float*)d_out;                   // (8, 512, 512) fp32

    unsigned short* T  = (unsigned short*)d_ws;                       // 1 MB bf16
    unsigned short* Pt = (unsigned short*)((char*)d_ws + (1 << 20));  // 256 KB bf16

    transpose_proj<<<16, 256, 0, stream>>>(proj, Pt);
    proj_mfma<<<256, 512, 0, stream>>>(batch, Pt, T);
    dist_mfma<<<dim3(8, 8, 8), 256, 0, stream>>>(T, out);
}

// Round 3
// 79.579 us; speedup vs baseline: 1.5305x; 1.0152x over previous
//
#include <hip/hip_runtime.h>

#define SEQ 512
#define MD  1024
#define RK  128

typedef __attribute__((ext_vector_type(8))) short  bf16x8;
typedef __attribute__((ext_vector_type(4))) float  floatx4;
typedef __attribute__((ext_vector_type(4))) unsigned int uint4v;
typedef __attribute__((ext_vector_type(4))) unsigned short ushortx4;

__device__ inline unsigned short f2bf(float f) {
    union { float f; unsigned u; } v; v.f = f;
    unsigned r = v.u + 0x7fffu + ((v.u >> 16) & 1u);   // RNE, inputs are normal
    return (unsigned short)(r >> 16);
}

// ---------- Kernel 0: Pt[n][k] = bf16(proj[k][n]), 128 x 1024 ----------
// 32 blocks: (k-chunk 64) x (n-half 64).
__global__ __launch_bounds__(256) void transpose_proj(
    const float* __restrict__ proj, unsigned short* __restrict__ Pt)
{
    __shared__ float Ls[64 * 68];    // 64 k x 64 n, pad 68
    const int t  = threadIdx.x;
    const int k0 = (blockIdx.x >> 1) * 64;
    const int n0 = (blockIdx.x & 1) * 64;

    {   // coalesced read of 64x64 fp32 tile
        int kr = t >> 2;
        int nc = (t & 3) * 16;
        #pragma unroll
        for (int c = 0; c < 4; ++c) {
            float4 v = *(const float4*)(proj + (size_t)(k0 + kr) * RK + n0 + nc + c * 4);
            *(float4*)(Ls + kr * 68 + nc + c * 4) = v;
        }
    }
    __syncthreads();
    {   // transposed write: thread -> row n, 16 k's
        int nl = t >> 2;
        int kh = (t & 3) * 16;
        unsigned short tmp[16];
        #pragma unroll
        for (int kk = 0; kk < 16; ++kk)
            tmp[kk] = f2bf(Ls[(kh + kk) * 68 + nl]);
        *(uint4v*)(Pt + (size_t)(n0 + nl) * MD + k0 + kh)     = *(uint4v*)(tmp);
        *(uint4v*)(Pt + (size_t)(n0 + nl) * MD + k0 + kh + 8) = *(uint4v*)(tmp + 8);
    }
}

// ---------- Kernel 1: T = bf16( batch @ proj ) + row norms, via MFMA ----------
// 256 blocks x 512 threads (8 waves). Block owns 16 rows; wave w owns a K-eighth.
// No K-loop barriers. One barrier before the conflict-free cross-wave reduce.
#define REDW 2112   // 16 * 132 floats per wave partial

__global__ __launch_bounds__(512) void proj_mfma(
    const float* __restrict__ batch, const unsigned short* __restrict__ Pt,
    unsigned short* __restrict__ T, float* __restrict__ Nrm)
{
    __shared__ float Red[8 * REDW];   // 67.6 KB

    const int t    = threadIdx.x;
    const int w    = t >> 6;
    const int l    = t & 63;
    const int lm   = l & 15;
    const int quad = l >> 4;
    const int r0   = blockIdx.x * 16;

    floatx4 acc[8];
    #pragma unroll
    for (int i = 0; i < 8; ++i) acc[i] = (floatx4){0.f, 0.f, 0.f, 0.f};

    const float* arow = batch + (size_t)(r0 + lm) * MD + w * 128 + quad * 8;

    #pragma unroll
    for (int s = 0; s < 4; ++s) {
        // A fragment: lane holds A[m=lm][k = w*128 + s*32 + quad*8 + j]
        float4 a0 = *(const float4*)(arow + s * 32);
        float4 a1 = *(const float4*)(arow + s * 32 + 4);
        bf16x8 av;
        av[0] = (short)f2bf(a0.x); av[1] = (short)f2bf(a0.y);
        av[2] = (short)f2bf(a0.z); av[3] = (short)f2bf(a0.w);
        av[4] = (short)f2bf(a1.x); av[5] = (short)f2bf(a1.y);
        av[6] = (short)f2bf(a1.z); av[7] = (short)f2bf(a1.w);
        #pragma unroll
        for (int nt = 0; nt < 8; ++nt) {
            bf16x8 bv = *(const bf16x8*)(Pt + (size_t)(nt * 16 + lm) * MD
                                         + w * 128 + s * 32 + quad * 8);
            acc[nt] = __builtin_amdgcn_mfma_f32_16x16x32_bf16(av, bv, acc[nt], 0, 0, 0);
        }
    }

    // dump per-wave partials; row stride 132 -> 2-way bank alias only (free)
    #pragma unroll
    for (int nt = 0; nt < 8; ++nt) {
        #pragma unroll
        for (int r = 0; r < 4; ++r) {
            Red[w * REDW + (quad * 4 + r) * 132 + nt * 16 + lm] = acc[nt][r];
        }
    }
    __syncthreads();

    // conflict-free b128 reduce: thread -> (row = t>>5, col4 = (t&31)*4)
    {
        const int row  = t >> 5;
        const int col4 = (t & 31) * 4;
        float4 s4 = {0.f, 0.f, 0.f, 0.f};
        #pragma unroll
        for (int ww = 0; ww < 8; ++ww) {
            float4 p = *(const float4*)(Red + ww * REDW + row * 132 + col4);
            s4.x += p.x; s4.y += p.y; s4.z += p.z; s4.w += p.w;
        }
        unsigned short tmp[4];
        tmp[0] = f2bf(s4.x); tmp[1] = f2bf(s4.y);
        tmp[2] = f2bf(s4.z); tmp[3] = f2bf(s4.w);
        *(ushortx4*)(T + (size_t)(r0 + row) * RK + col4) = *(ushortx4*)tmp;

        // fused row norm: reduce ||T_row||^2 across the 32 lanes owning the row
        float ss = s4.x * s4.x + s4.y * s4.y + s4.z * s4.z + s4.w * s4.w;
        ss += __shfl_xor(ss, 1,  64);
        ss += __shfl_xor(ss, 2,  64);
        ss += __shfl_xor(ss, 4,  64);
        ss += __shfl_xor(ss, 8,  64);
        ss += __shfl_xor(ss, 16, 64);
        if ((t & 31) == 0) Nrm[r0 + row] = ss;
    }
}

// ---------- Kernel 2: D[b,i,j] = nI + nJ - 2 * (T_i . T_j), via MFMA ----------
// Grid (8 jt, 8 it, 8 b), 256 threads = 4 waves; 64x64 tile; wave w -> 16 i-rows.
// Single barrier: norms pre-computed, loaded during staging.
#define LDB 136   // 128 + 8 bf16 pad: 16B rows, stride/16B odd -> 2-way alias only

__global__ __launch_bounds__(256) void dist_mfma(
    const unsigned short* __restrict__ T, const float* __restrict__ Nrm,
    float* __restrict__ out)
{
    __shared__ unsigned short Ti[64 * LDB];
    __shared__ unsigned short Tj[64 * LDB];
    __shared__ float nI[64], nJ[64];

    const int t    = threadIdx.x;
    const int w    = t >> 6;
    const int l    = t & 63;
    const int lm   = l & 15;
    const int quad = l >> 4;
    const int jt = blockIdx.x, it = blockIdx.y, b = blockIdx.z;
    const int i0 = it * 64, j0 = jt * 64;
    const unsigned short* Tb = T + (size_t)b * SEQ * RK;

    {   // stage both 64x128 bf16 tiles + norms
        int row = t >> 2, kq = (t & 3) * 32;
        const unsigned short* si = Tb + (size_t)(i0 + row) * RK + kq;
        const unsigned short* sj = Tb + (size_t)(j0 + row) * RK + kq;
        #pragma unroll
        for (int q = 0; q < 4; ++q) {
            *(uint4v*)(Ti + row * LDB + kq + q * 8) = *(const uint4v*)(si + q * 8);
            *(uint4v*)(Tj + row * LDB + kq + q * 8) = *(const uint4v*)(sj + q * 8);
        }
        if (t < 64)                nI[t]      = Nrm[(size_t)b * SEQ + i0 + t];
        else if (t < 128)          nJ[t - 64] = Nrm[(size_t)b * SEQ + j0 + (t - 64)];
    }
    __syncthreads();

    floatx4 acc[4];
    #pragma unroll
    for (int i = 0; i < 4; ++i) acc[i] = (floatx4){0.f, 0.f, 0.f, 0.f};

    #pragma unroll
    for (int s = 0; s < 4; ++s) {
        bf16x8 av = *(const bf16x8*)(Ti + (w * 16 + lm) * LDB + s * 32 + quad * 8);
        #pragma unroll
        for (int nt = 0; nt < 4; ++nt) {
            bf16x8 bv = *(const bf16x8*)(Tj + (nt * 16 + lm) * LDB + s * 32 + quad * 8);
            acc[nt] = __builtin_amdgcn_mfma_f32_16x16x32_bf16(av, bv, acc[nt], 0, 0, 0);
        }
    }

    float niv[4];
    #pragma unroll
    for (int r = 0; r < 4; ++r) niv[r] = nI[w * 16 + quad * 4 + r];

    float* ob = out + ((size_t)b * SEQ + (i0 + w * 16)) * SEQ + j0;
    #pragma unroll
    for (int nt = 0; nt < 4; ++nt) {
        float njv = nJ[nt * 16 + lm];
        #pragma unroll
        for (int r = 0; r < 4; ++r) {
            ob[(size_t)(quad * 4 + r) * SEQ + nt * 16 + lm] =
                niv[r] + njv - 2.f * acc[nt][r];
        }
    }
}

extern "C" void kernel_launch(void* const* d_in, const int* in_sizes, int n_in,
                              void* d_out, int out_size, void* d_ws, size_t ws_size,
                              hipStream_t stream) {
    const float* batch = (const float*)d_in[0];   // (8, 512, 1024) fp32
    const float* proj  = (const float*)d_in[1];   // (1024, 128) fp32
    float* out = (float*)d_out;                   // (8, 512, 512) fp32

    unsigned short* T   = (unsigned short*)d_ws;                          // 1 MB bf16
    unsigned short* Pt  = (unsigned short*)((char*)d_ws + (1 << 20));     // 256 KB bf16
    float*          Nrm = (float*)((char*)d_ws + (1 << 20) + (1 << 18));  // 16 KB fp32

    transpose_proj<<<32, 256, 0, stream>>>(proj, Pt);
    proj_mfma<<<256, 512, 0, stream>>>(batch, Pt, T, Nrm);
    dist_mfma<<<dim3(8, 8, 8), 256, 0, stream>>>(T, Nrm, out);
}